// Round 5
// baseline (571.596 us; speedup 1.0000x reference)
//
#include <hip/hip_runtime.h>
#include <math.h>

#define BN    8
#define NN    1024
#define ADIM  8
#define STEPS 5
#define K2    2048                 // N*E
#define ROWS  (BN*NN)              // 8192

typedef __attribute__((ext_vector_type(8))) short bf16x8;
typedef __attribute__((ext_vector_type(4))) float f32x4;

__device__ __forceinline__ unsigned short f2bf(float f) {
    unsigned int u = __float_as_uint(f);
    u += 0x7FFF + ((u >> 16) & 1);          // round-to-nearest-even
    return (unsigned short)(u >> 16);
}

// ---------------- one-time: adjacency fp32 -> bf16 ----------------
__global__ __launch_bounds__(256) void conv_adj(
    const float* __restrict__ in, unsigned short* __restrict__ out)
{
    int tid = blockIdx.x * 256 + threadIdx.x;     // 0..2097151
    #pragma unroll
    for (int i = 0; i < 4; ++i) {
        size_t idx = (size_t)tid + (size_t)i * 2097152;
        float4 v = ((const float4*)in)[idx];
        ushort4 o;
        o.x = f2bf(v.x); o.y = f2bf(v.y); o.z = f2bf(v.z); o.w = f2bf(v.w);
        ((ushort4*)out)[idx] = o;
    }
}

// ---------------- init: h_ws = initial_state; edge0 = f(initial_state) ----------
__global__ __launch_bounds__(256) void init_kernel(
    const float* __restrict__ init_state,
    const float* __restrict__ We, const float* __restrict__ be,
    float* __restrict__ h_ws, unsigned short* __restrict__ edge_t)
{
    __shared__ float h_lds[4][65];
    int t = threadIdx.x;
    int r = t >> 6, hp = t & 63;
    int row = blockIdx.x * 4 + r;
    float hv = init_state[(size_t)row * 64 + hp];
    h_ws[(size_t)row * 64 + hp] = hv;
    h_lds[r][hp] = hv;
    __syncthreads();
    int b = row >> 10, n = row & 1023;
    #pragma unroll
    for (int e = 0; e < 2; ++e) {
        float acc = be[hp * 2 + e];
        #pragma unroll 8
        for (int c = 0; c < 64; ++c)
            acc += h_lds[r][c] * We[c * 128 + hp * 2 + e];
        edge_t[((size_t)b * 64 + hp) * K2 + e * NN + n] = f2bf(acc);
    }
}

// ---------------- fused step: gemm (full-K) + gate + edge, 16 rows/block ----------
// grid = 512. waves: w=0,1 -> a_in (K-half 0/1); w=2,3 -> a_out (K-half 0/1).
__global__ __launch_bounds__(256, 2) void step_kernel(
    const unsigned short* __restrict__ adjb,     // [b][n][4096] bf16
    const unsigned short* __restrict__ edge_in,  // [b][64][2048] bf16
    const float* __restrict__ Wg, const float* __restrict__ bg,
    const float* __restrict__ We, const float* __restrict__ be,
    float* __restrict__ h_ws,
    unsigned short* __restrict__ edge_out,
    int compute_edge)
{
    __shared__ float smem[12544];       // 50176 B
    float* Wg_l = smem;                 // 8192 floats (chunk area, 32 KB)
    float* red  = smem + 8192;          // 4 * 16 * 68 = 4352 floats

    int t = threadIdx.x, bid = blockIdx.x;

    // prefetch Wg rows 0..127 (overlaps gemm; no barrier until after gemm)
    #pragma unroll
    for (int l = 0; l < 8; ++l) {
        int idx = t + l * 256;
        *(float4*)&Wg_l[idx * 4] = *(const float4*)&Wg[idx * 4];
    }

    // ---- gemm: full K, B-frags direct from L2, A-frags direct from L3 ----
    int w = t >> 6, lane = t & 63, l15 = lane & 15, q = lane >> 4;
    int dir = w >> 1, kh = w & 1;
    int b = bid >> 6;                   // 16 rows/block, 64 blocks/batch
    const unsigned short* Ap = adjb + ((size_t)(bid * 16 + l15)) * 4096
                                    + dir * K2 + kh * 1024 + q * 8;
    const unsigned short* Bp = edge_in + (size_t)b * 64 * K2 + kh * 1024 + q * 8;

    f32x4 acc[4];
    #pragma unroll
    for (int ct = 0; ct < 4; ++ct) acc[ct] = (f32x4){0.f, 0.f, 0.f, 0.f};

    #pragma unroll 4
    for (int ks = 0; ks < 32; ++ks) {
        bf16x8 af = *(const bf16x8*)(Ap + ks * 32);
        #pragma unroll
        for (int ct = 0; ct < 4; ++ct) {
            bf16x8 bfr = *(const bf16x8*)(Bp + (size_t)(ct * 16 + l15) * K2 + ks * 32);
            acc[ct] = __builtin_amdgcn_mfma_f32_16x16x32_bf16(af, bfr, acc[ct], 0, 0, 0);
        }
    }

    // partials -> LDS. C/D layout: col = lane&15, row = (lane>>4)*4 + reg
    {
        float* rw = red + w * (16 * 68);
        #pragma unroll
        for (int ct = 0; ct < 4; ++ct)
            #pragma unroll
            for (int i = 0; i < 4; ++i)
                rw[(q * 4 + i) * 68 + ct * 16 + l15] = acc[ct][i];
    }
    __syncthreads();

    // ---- repurpose red: red0 = a_in, red1 = h_old, red2 = a_out ----
    int rloc = t >> 4, jq = t & 15;
    int row = bid * 16 + rloc;
    size_t off = (size_t)row * 64 + jq * 4;
    float4 hold = *(const float4*)(h_ws + off);
    float hv4[4] = {hold.x, hold.y, hold.z, hold.w};
    #pragma unroll
    for (int i = 0; i < 4; ++i) {
        int h = jq * 4 + i;
        float s_in  = red[0 * 1088 + rloc * 68 + h] + red[1 * 1088 + rloc * 68 + h];
        float s_out = red[2 * 1088 + rloc * 68 + h] + red[3 * 1088 + rloc * 68 + h];
        red[0 * 1088 + rloc * 68 + h] = s_in;      // own elements only - no race
        red[2 * 1088 + rloc * 68 + h] = s_out;
        red[1 * 1088 + rloc * 68 + h] = hv4[i];
    }
    __syncthreads();

    // ---- gate part 1: k<128 with Wg rows 0..127 (already staged) ----
    float acc4[4] = {0.f, 0.f, 0.f, 0.f};
    #pragma unroll 8
    for (int k = 0; k < 64; ++k) {
        float av = red[0 * 1088 + rloc * 68 + k];
        float4 wg = *(const float4*)&Wg_l[k * 64 + jq * 4];
        acc4[0] += av * wg.x; acc4[1] += av * wg.y;
        acc4[2] += av * wg.z; acc4[3] += av * wg.w;
    }
    #pragma unroll 8
    for (int k = 0; k < 64; ++k) {
        float av = red[2 * 1088 + rloc * 68 + k];
        float4 wg = *(const float4*)&Wg_l[(64 + k) * 64 + jq * 4];
        acc4[0] += av * wg.x; acc4[1] += av * wg.y;
        acc4[2] += av * wg.z; acc4[3] += av * wg.w;
    }
    __syncthreads();
    // restage Wg rows 128..191 into first 4096 floats of chunk area
    #pragma unroll
    for (int l = 0; l < 4; ++l) {
        int idx = t + l * 256;
        *(float4*)&Wg_l[idx * 4] = *(const float4*)&Wg[8192 + idx * 4];
    }
    __syncthreads();

    float zp[4] = {acc4[0], acc4[1], acc4[2], acc4[3]};
    #pragma unroll 8
    for (int k = 0; k < 64; ++k) {
        float hv = red[1 * 1088 + rloc * 68 + k];
        float4 wg = *(const float4*)&Wg_l[k * 64 + jq * 4];
        zp[0] += hv * wg.x; zp[1] += hv * wg.y;
        zp[2] += hv * wg.z; zp[3] += hv * wg.w;
    }
    float4 bgv = *(const float4*)(bg + jq * 4);
    float bg4[4] = {bgv.x, bgv.y, bgv.z, bgv.w};
    float z[4], zh[4];
    #pragma unroll
    for (int i = 0; i < 4; ++i) {
        z[i]  = 1.f / (1.f + __expf(-(zp[i] + bg4[i])));
        zh[i] = z[i] * hv4[i];
    }
    int gbase = lane & 48;
    #pragma unroll
    for (int k = 0; k < 64; ++k) {
        float zhk = __shfl(zh[k & 3], gbase | (k >> 2), 64);
        float4 wg = *(const float4*)&Wg_l[k * 64 + jq * 4];
        acc4[0] += zhk * wg.x; acc4[1] += zhk * wg.y;
        acc4[2] += zhk * wg.z; acc4[3] += zhk * wg.w;
    }
    float hn[4];
    #pragma unroll
    for (int i = 0; i < 4; ++i) {
        float ht = tanhf(acc4[i] + bg4[i]);
        hn[i] = (1.f - z[i]) * hv4[i] + z[i] * ht;
    }
    *(float4*)(h_ws + off) = make_float4(hn[0], hn[1], hn[2], hn[3]);

    // ---- edge projection for next step ----
    if (compute_edge) {
        __syncthreads();            // all Wg_l / red reads done
        float* We_l = smem;         // 8192 floats
        float* h_e  = red;          // [16][65]
        #pragma unroll
        for (int l = 0; l < 8; ++l) {
            int idx = t + l * 256;
            *(float4*)&We_l[idx * 4] = *(const float4*)&We[idx * 4];
        }
        h_e[rloc * 65 + jq * 4 + 0] = hn[0]; h_e[rloc * 65 + jq * 4 + 1] = hn[1];
        h_e[rloc * 65 + jq * 4 + 2] = hn[2]; h_e[rloc * 65 + jq * 4 + 3] = hn[3];
        __syncthreads();
        float eacc[8];
        #pragma unroll
        for (int m = 0; m < 8; ++m) eacc[m] = be[jq * 8 + m];
        #pragma unroll 4
        for (int c = 0; c < 64; ++c) {
            float hv = h_e[rloc * 65 + c];
            float4 w0 = *(const float4*)&We_l[c * 128 + jq * 8];
            float4 w1 = *(const float4*)&We_l[c * 128 + jq * 8 + 4];
            eacc[0] += hv * w0.x; eacc[1] += hv * w0.y; eacc[2] += hv * w0.z; eacc[3] += hv * w0.w;
            eacc[4] += hv * w1.x; eacc[5] += hv * w1.y; eacc[6] += hv * w1.z; eacc[7] += hv * w1.w;
        }
        int bb = row >> 10, n = row & 1023;
        #pragma unroll
        for (int m = 0; m < 8; ++m) {
            int o = jq * 8 + m;
            int hp = o >> 1, e = o & 1;
            edge_out[((size_t)bb * 64 + hp) * K2 + e * NN + n] = f2bf(eacc[m]);
        }
    }
}

// ---------------- output head ----------
__global__ __launch_bounds__(256) void head_kernel(
    const float* __restrict__ h_ws, const float* __restrict__ ann,
    const float* __restrict__ Wh, const float* __restrict__ bh,
    const float* __restrict__ Wo, const float* __restrict__ bo,
    float* __restrict__ out)
{
    __shared__ float Wh_l[72 * 64];
    __shared__ float ha[4][73];
    int t = threadIdx.x;
    #pragma unroll
    for (int l = 0; l < 18; ++l) {
        int idx = t + l * 256;
        Wh_l[idx] = Wh[idx];
    }
    int r = t >> 6, hp = t & 63;
    int row = blockIdx.x * 4 + r;
    ha[r][hp] = h_ws[(size_t)row * 64 + hp];
    if (hp < ADIM) ha[r][64 + hp] = ann[(size_t)row * ADIM + hp];
    __syncthreads();

    float acc = bh[hp];
    #pragma unroll 8
    for (int k = 0; k < 72; ++k)
        acc += ha[r][k] * Wh_l[k * 64 + hp];
    float v = tanhf(acc) * Wo[hp];
    #pragma unroll
    for (int o = 32; o; o >>= 1) v += __shfl_down(v, o, 64);
    if (hp == 0) out[row] = v + bo[0];
}

extern "C" void kernel_launch(void* const* d_in, const int* in_sizes, int n_in,
                              void* d_out, int out_size, void* d_ws, size_t ws_size,
                              hipStream_t stream) {
    const float* init_state = (const float*)d_in[0];
    const float* ann = (const float*)d_in[1];
    const float* adj = (const float*)d_in[2];
    const float* We  = (const float*)d_in[3];
    const float* be  = (const float*)d_in[4];
    const float* Wg  = (const float*)d_in[5];
    const float* bg  = (const float*)d_in[6];
    const float* Wh  = (const float*)d_in[7];
    const float* bh  = (const float*)d_in[8];
    const float* Wo  = (const float*)d_in[9];
    const float* bo  = (const float*)d_in[10];
    float* out = (float*)d_out;

    // ws: adj_bf 64 MB | edge0 2 MB | edge1 2 MB | h_ws 2 MB
    char* wsb = (char*)d_ws;
    unsigned short* adj_bf = (unsigned short*)wsb;
    unsigned short* edge0  = (unsigned short*)(wsb + 67108864);
    unsigned short* edge1  = (unsigned short*)(wsb + 67108864 + 2097152);
    float* h_ws = (float*)(wsb + 67108864 + 2097152 + 2097152);
    unsigned short* ebuf[2] = {edge0, edge1};

    conv_adj<<<dim3(8192), dim3(256), 0, stream>>>(adj, adj_bf);
    init_kernel<<<dim3(ROWS / 4), dim3(256), 0, stream>>>(init_state, We, be, h_ws, edge0);
    for (int s = 0; s < STEPS; ++s) {
        step_kernel<<<dim3(512), dim3(256), 0, stream>>>(
            adj_bf, ebuf[s & 1], Wg, bg, We, be, h_ws,
            ebuf[(s + 1) & 1], (s < STEPS - 1) ? 1 : 0);
    }
    head_kernel<<<dim3(ROWS / 4), dim3(256), 0, stream>>>(h_ws, ann, Wh, bh, Wo, bo, out);
}